// Round 17
// baseline (198.200 us; speedup 1.0000x reference)
//
#include <hip/hip_runtime.h>
#include <hip/hip_bf16.h>

// Round 17: round-16 config (196.8us) with one change: qkv staging issues all
// 6 chunk loads upfront (12 global_load_dwordx4 back-to-back), then converts
// and writes. One HBM latency instead of ~6 serialized; in-order vmcnt
// retirement drains oldest-first as the write loop consumes them.

typedef __attribute__((ext_vector_type(8))) short bf16x8;
typedef __attribute__((ext_vector_type(4))) float f32x4;

#define B_ 1024
#define T_ 256
#define C_ 384
#define H_ 64

static __device__ __forceinline__ unsigned short f2bf(float f) {
  unsigned int u = __float_as_uint(f);
  return (unsigned short)((u + 0x7fffu + ((u >> 16) & 1u)) >> 16);
}

static __device__ __forceinline__ float bf2f(unsigned short h) {
  return __uint_as_float(((unsigned int)h) << 16);
}

static __device__ __forceinline__ bf16x8 cvt8(float4 a, float4 b) {
  union { __hip_bfloat162 h[4]; bf16x8 v; } u;
  u.h[0] = __float22bfloat162_rn(make_float2(a.x, a.y));
  u.h[1] = __float22bfloat162_rn(make_float2(a.z, a.w));
  u.h[2] = __float22bfloat162_rn(make_float2(b.x, b.y));
  u.h[3] = __float22bfloat162_rn(make_float2(b.z, b.w));
  return u.v;
}

// wtp fragment-linear: wtp[((ks*12+nt)*64 + lane)*8 + i] =
//   bf16( W'[n = nt*16 + (lane&15)][k = ks*32 + (lane>>4)*8 + i] )
__global__ void pack_w_frag(const float* __restrict__ Wq, const float* __restrict__ Wk,
                            const float* __restrict__ Wv, unsigned short* __restrict__ wtp) {
  int id = blockIdx.x * 256 + threadIdx.x;
  if (id >= 144 * 512) return;
  int i = id & 7, lane = (id >> 3) & 63, f = id >> 9;
  int nt = f % 12, ks = f / 12;
  int n = nt * 16 + (lane & 15);
  int k = ks * 32 + (lane >> 4) * 8 + i;
  const float* W = (n < 64) ? Wq : ((n < 128) ? Wk : Wv);
  wtp[id] = f2bf(W[k * 64 + (n & 63)]);
}

// Q/K packed frag layout: qp[(((b*16+tile)*2+ks2)*64 + L)*8 + i] =
//   Q[b][tile*16 + (L&15)][ks2*32 + (L>>4)*8 + i]   (RoPE applied)
// V packed frag (transposed): vp[(((b*4+nt)*8+ksg)*64 + L)*8 + i] =
//   V[b][ksg*32 + (L>>4)*8 + i][nt*16 + (L&15)]
__launch_bounds__(512, 6)
__global__ void qkv_kernel(const float* __restrict__ x, const float* __restrict__ cosp,
                           const float* __restrict__ sinp,
                           const unsigned short* __restrict__ wtp,
                           unsigned short* __restrict__ qp,
                           unsigned short* __restrict__ kp,
                           unsigned short* __restrict__ vp) {
  // 48 KB total: x slab; after the K-loop the same region is reused as the
  // Q/K/V staging tiles (one extra barrier).
  __shared__ __align__(16) unsigned short xs[64 * 384];

  unsigned short* Qst = xs;                 // [64][72]
  unsigned short* Kst = xs + 64 * 72;       // [64][72]
  unsigned short* Vst = xs + 2 * 64 * 72;   // [64][72]

  const int tid = threadIdx.x;
  const int w = tid >> 6;        // wave 0..7
  const int lane = tid & 63;
  const int l15 = lane & 15;
  const int lq = lane >> 4;
  const int bk = blockIdx.x;     // 0..4095
  const int b = bk >> 2, g64 = bk & 3;
  const int row0 = g64 * 64;

  const float* xb = x + (size_t)b * T_ * C_ + (size_t)row0 * C_;

  // ---- stage x slab: issue ALL 6 chunk loads upfront (one latency, then
  // pipelined streaming), convert+write after.
  {
    float4 c[6][2];
    #pragma unroll
    for (int s = 0; s < 6; ++s) {
      const float* p = xb + (size_t)(s * 512 + tid) * 8;
      c[s][0] = *(const float4*)p;
      c[s][1] = *(const float4*)(p + 4);
    }
    #pragma unroll
    for (int s = 0; s < 6; ++s) {
      int cc = s * 512 + tid;
      int row = cc / 48;                 // 48 chunks per row
      int cb = (cc - row * 48) * 16;     // byte offset within bf16 row
      *(bf16x8*)((char*)xs + row * 768 + (cb ^ ((row & 7) << 4))) = cvt8(c[s][0], c[s][1]);
    }
  }
  __syncthreads();

  // ---- K-loop: wave = (rset = w>>2) x (ng = w&3); 2 row-tiles x 3 n-tiles.
  const int ng = w & 3, rset = w >> 2;

  f32x4 acc[2][3];
  #pragma unroll
  for (int i = 0; i < 2; ++i)
    #pragma unroll
    for (int m = 0; m < 3; ++m) {
      f32x4 z = {0.f, 0.f, 0.f, 0.f};
      acc[i][m] = z;
    }

  const int arow0 = (rset * 2) * 16 + l15;
  const int arow1 = (rset * 2 + 1) * 16 + l15;
  const char* xrow0 = (const char*)xs + arow0 * 768;
  const char* xrow1 = (const char*)xs + arow1 * 768;
  const int asw0 = (arow0 & 7) << 4;
  const int asw1 = (arow1 & 7) << 4;

  #pragma unroll
  for (int ks = 0; ks < 12; ++ks) {
    bf16x8 bv[3];
    #pragma unroll
    for (int m = 0; m < 3; ++m)
      bv[m] = *(const bf16x8*)(wtp + ((size_t)(ks * 12 + ng * 3 + m) * 64 + lane) * 8);
    bf16x8 a0 = *(const bf16x8*)(xrow0 + ((ks * 64 + lq * 16) ^ asw0));
    bf16x8 a1 = *(const bf16x8*)(xrow1 + ((ks * 64 + lq * 16) ^ asw1));
    #pragma unroll
    for (int m = 0; m < 3; ++m) {
      acc[0][m] = __builtin_amdgcn_mfma_f32_16x16x32_bf16(a0, bv[m], acc[0][m], 0, 0, 0);
      acc[1][m] = __builtin_amdgcn_mfma_f32_16x16x32_bf16(a1, bv[m], acc[1][m], 0, 0, 0);
    }
  }
  __syncthreads();   // all waves done reading xs before it is overwritten

  // ---- scatter-stage accumulators (pre-RoPE) into staging tiles (xs region)
  #pragma unroll
  for (int i = 0; i < 2; ++i) {
    #pragma unroll
    for (int m = 0; m < 3; ++m) {
      const int nt = ng * 3 + m;
      #pragma unroll
      for (int j = 0; j < 4; ++j) {
        const int r64 = (rset * 2 + i) * 16 + lq * 4 + j;
        unsigned short v = f2bf(acc[i][m][j]);
        if (nt < 4)      Qst[r64 * 72 + nt * 16 + l15] = v;
        else if (nt < 8) Kst[r64 * 72 + (nt - 4) * 16 + l15] = v;
        else             Vst[((nt - 8) * 16 + l15) * 72 + r64] = v;
      }
    }
  }
  __syncthreads();

  // ---- frag-line writeout: 24 x 1KB lines (Q 8, K 8, V 8); RoPE fused on Q/K
  #pragma unroll
  for (int pass = 0; pass < 3; ++pass) {
    const int id = pass * 8 + w;
    if (id < 16) {
      const unsigned short* S = (id < 8) ? Qst : Kst;
      unsigned short* dst = (id < 8) ? qp : kp;
      const int lid = id & 7;
      const int tl = lid >> 1;          // tile within 64-row slab (0..3)
      const int ks2 = lid & 1;
      const int r64 = tl * 16 + l15;
      const int c0 = ks2 * 32 + lq * 8;
      const unsigned short* rowp = S + r64 * 72;
      bf16x8 mv = *(const bf16x8*)(rowp + c0);
      bf16x8 pv = *(const bf16x8*)(rowp + (c0 ^ 32));
      const int tglob = row0 + r64;
      const float* cp = cosp + tglob * H_ + c0;
      const float* sp = sinp + tglob * H_ + c0;
      float4 ca = *(const float4*)cp, cb = *(const float4*)(cp + 4);
      float4 sa = *(const float4*)sp, sb = *(const float4*)(sp + 4);
      const float sgn = ks2 ? 1.0f : -1.0f;
      bf16x8 ov;
      ov[0] = (short)f2bf(bf2f((unsigned short)mv[0]) * ca.x + sgn * bf2f((unsigned short)pv[0]) * sa.x);
      ov[1] = (short)f2bf(bf2f((unsigned short)mv[1]) * ca.y + sgn * bf2f((unsigned short)pv[1]) * sa.y);
      ov[2] = (short)f2bf(bf2f((unsigned short)mv[2]) * ca.z + sgn * bf2f((unsigned short)pv[2]) * sa.z);
      ov[3] = (short)f2bf(bf2f((unsigned short)mv[3]) * ca.w + sgn * bf2f((unsigned short)pv[3]) * sa.w);
      ov[4] = (short)f2bf(bf2f((unsigned short)mv[4]) * cb.x + sgn * bf2f((unsigned short)pv[4]) * sb.x);
      ov[5] = (short)f2bf(bf2f((unsigned short)mv[5]) * cb.y + sgn * bf2f((unsigned short)pv[5]) * sb.y);
      ov[6] = (short)f2bf(bf2f((unsigned short)mv[6]) * cb.z + sgn * bf2f((unsigned short)pv[6]) * sb.z);
      ov[7] = (short)f2bf(bf2f((unsigned short)mv[7]) * cb.w + sgn * bf2f((unsigned short)pv[7]) * sb.w);
      const int tile_glob = g64 * 4 + tl;
      *(bf16x8*)(dst + ((((size_t)b * 16 + tile_glob) * 2 + ks2) * 64 + lane) * 8) = ov;
    } else if (id < 24) {
      const int lid = id - 16;
      const int ntv = lid >> 1;
      const int kgl = lid & 1;          // which 32-row half of the slab
      const int ksg = g64 * 2 + kgl;
      bf16x8 fr = *(const bf16x8*)(Vst + (ntv * 16 + l15) * 72 + kgl * 32 + lq * 8);
      *(bf16x8*)(vp + ((((size_t)b * 4 + ntv) * 8 + ksg) * 64 + lane) * 8) = fr;
    }
  }
}

__launch_bounds__(256, 4)
__global__ void attn_kernel(const unsigned short* __restrict__ qp,
                            const unsigned short* __restrict__ kp,
                            const unsigned short* __restrict__ vp,
                            float* __restrict__ out) {
  __shared__ unsigned short Plds[4 * 16 * 264];

  const int tid = threadIdx.x;
  const int w = tid >> 6;
  const int lane = tid & 63;
  const int l15 = lane & 15;
  const int lq = lane >> 4;
  // Same-XCD pairing: blocks b and b+1024 (same batch) share an XCD
  // (1024 % 8 == 0 under round-robin) -> overlapping K/V reads hit L2.
  const int bk = blockIdx.x;
  const int b = bk & 1023, half = bk >> 10;
  const int rt2[2] = {half * 8 + w, half * 8 + 7 - w};

  unsigned short* Pw = Plds + w * 16 * 264;
  float* ob = out + (size_t)b * T_ * H_;

  #pragma unroll
  for (int i = 0; i < 2; ++i) {
    const int ti = rt2[i];
    const int t0 = ti * 16;

    bf16x8 aq[2];
    #pragma unroll
    for (int ks2 = 0; ks2 < 2; ++ks2)
      aq[ks2] = *(const bf16x8*)(qp + ((((size_t)b * 16 + ti) * 2 + ks2) * 64 + lane) * 8);

    f32x4 sacc[16];
    #pragma unroll
    for (int si = 0; si < 16; ++si) {
      f32x4 z = {0.f, 0.f, 0.f, 0.f};
      sacc[si] = z;
    }

    #pragma unroll
    for (int si = 0; si < 16; ++si) {
      if (si <= ti) {  // wave-uniform causal tile skip
        #pragma unroll
        for (int ks2 = 0; ks2 < 2; ++ks2) {
          bf16x8 bkf = *(const bf16x8*)(kp + ((((size_t)b * 16 + si) * 2 + ks2) * 64 + lane) * 8);
          sacc[si] = __builtin_amdgcn_mfma_f32_16x16x32_bf16(aq[ks2], bkf, sacc[si], 0, 0, 0);
        }
      }
    }

    int trow = t0 + lq * 4;
    #pragma unroll
    for (int si = 0; si < 16; ++si) {
      #pragma unroll
      for (int j = 0; j < 4; ++j) {
        float s = sacc[si][j] * 0.125f;
        if (si * 16 + l15 > trow + j) s = -1e30f;
        sacc[si][j] = s;
      }
    }

    float rl[4];
    #pragma unroll
    for (int j = 0; j < 4; ++j) {
      float mj = -1e30f;
      #pragma unroll
      for (int si = 0; si < 16; ++si) mj = fmaxf(mj, sacc[si][j]);
      #pragma unroll
      for (int d = 1; d < 16; d <<= 1) mj = fmaxf(mj, __shfl_xor(mj, d));
      float lj = 0.0f;
      #pragma unroll
      for (int si = 0; si < 16; ++si) {
        float p = __expf(sacc[si][j] - mj);
        lj += p;
        Pw[(lq * 4 + j) * 264 + si * 16 + l15] = f2bf(p);
      }
      #pragma unroll
      for (int d = 1; d < 16; d <<= 1) lj += __shfl_xor(lj, d);
      rl[j] = 1.0f / lj;
    }

    f32x4 oacc[4];
    #pragma unroll
    for (int nt = 0; nt < 4; ++nt) {
      f32x4 z = {0.f, 0.f, 0.f, 0.f};
      oacc[nt] = z;
    }
    int nk = (t0 + 16 + 31) >> 5;
    for (int ks = 0; ks < nk; ++ks) {
      bf16x8 ap = *(const bf16x8*)&Pw[l15 * 264 + ks * 32 + lq * 8];
      #pragma unroll
      for (int nt = 0; nt < 4; ++nt) {
        bf16x8 bv = *(const bf16x8*)(vp + ((((size_t)b * 4 + nt) * 8 + ks) * 64 + lane) * 8);
        oacc[nt] = __builtin_amdgcn_mfma_f32_16x16x32_bf16(ap, bv, oacc[nt], 0, 0, 0);
      }
    }

    #pragma unroll
    for (int nt = 0; nt < 4; ++nt)
      #pragma unroll
      for (int j = 0; j < 4; ++j)
        ob[(t0 + lq * 4 + j) * H_ + nt * 16 + l15] = oacc[nt][j] * rl[j];
  }
}

extern "C" void kernel_launch(void* const* d_in, const int* in_sizes, int n_in,
                              void* d_out, int out_size, void* d_ws, size_t ws_size,
                              hipStream_t stream) {
  const float* x    = (const float*)d_in[0];
  const float* cosp = (const float*)d_in[1];
  const float* sinp = (const float*)d_in[2];
  const float* Wq   = (const float*)d_in[3];
  const float* Wk   = (const float*)d_in[4];
  const float* Wv   = (const float*)d_in[5];
  float* out = (float*)d_out;

  const size_t wtp_bytes = 144 * 512 * 2;
  const size_t frag_elems = (size_t)B_ * 16 * 2 * 64 * 8;

  unsigned short* wtp = (unsigned short*)d_ws;
  unsigned short* qp = (unsigned short*)((char*)d_ws + wtp_bytes);
  unsigned short* kp = qp + frag_elems;
  unsigned short* vp = kp + frag_elems;
  (void)ws_size;

  pack_w_frag<<<288, 256, 0, stream>>>(Wq, Wk, Wv, wtp);
  qkv_kernel<<<4096, 512, 0, stream>>>(x, cosp, sinp, wtp, qp, kp, vp);
  attn_kernel<<<B_ * 2, 256, 0, stream>>>(qp, kp, vp, out);
}

// Round 18
// 196.313 us; speedup vs baseline: 1.0096x; 1.0096x over previous
//
#include <hip/hip_runtime.h>
#include <hip/hip_bf16.h>

// FINAL (round-16 config, measured 196.8us): split architecture.
//  pack_w_frag: W -> fragment-linear bf16 (L2-resident, coalesced lane*16 reads)
//  qkv_kernel:  64-row slab -> LDS (depth-2 reg staging, XOR-swz), K-loop from
//               LDS + L2 wtp, staging tiles alias the slab (48KB -> 3 blk/CU),
//               frag-line coalesced writeout with fused RoPE.
//  attn_kernel: frag-packed Q/K/V reads (lane*16, L2/L3), register softmax,
//               causal tile skip, PV with K-step truncation, same-XCD pairing.

typedef __attribute__((ext_vector_type(8))) short bf16x8;
typedef __attribute__((ext_vector_type(4))) float f32x4;

#define B_ 1024
#define T_ 256
#define C_ 384
#define H_ 64

static __device__ __forceinline__ unsigned short f2bf(float f) {
  unsigned int u = __float_as_uint(f);
  return (unsigned short)((u + 0x7fffu + ((u >> 16) & 1u)) >> 16);
}

static __device__ __forceinline__ float bf2f(unsigned short h) {
  return __uint_as_float(((unsigned int)h) << 16);
}

static __device__ __forceinline__ bf16x8 cvt8(float4 a, float4 b) {
  union { __hip_bfloat162 h[4]; bf16x8 v; } u;
  u.h[0] = __float22bfloat162_rn(make_float2(a.x, a.y));
  u.h[1] = __float22bfloat162_rn(make_float2(a.z, a.w));
  u.h[2] = __float22bfloat162_rn(make_float2(b.x, b.y));
  u.h[3] = __float22bfloat162_rn(make_float2(b.z, b.w));
  return u.v;
}

// wtp fragment-linear: wtp[((ks*12+nt)*64 + lane)*8 + i] =
//   bf16( W'[n = nt*16 + (lane&15)][k = ks*32 + (lane>>4)*8 + i] )
__global__ void pack_w_frag(const float* __restrict__ Wq, const float* __restrict__ Wk,
                            const float* __restrict__ Wv, unsigned short* __restrict__ wtp) {
  int id = blockIdx.x * 256 + threadIdx.x;
  if (id >= 144 * 512) return;
  int i = id & 7, lane = (id >> 3) & 63, f = id >> 9;
  int nt = f % 12, ks = f / 12;
  int n = nt * 16 + (lane & 15);
  int k = ks * 32 + (lane >> 4) * 8 + i;
  const float* W = (n < 64) ? Wq : ((n < 128) ? Wk : Wv);
  wtp[id] = f2bf(W[k * 64 + (n & 63)]);
}

// Q/K packed frag layout: qp[(((b*16+tile)*2+ks2)*64 + L)*8 + i] =
//   Q[b][tile*16 + (L&15)][ks2*32 + (L>>4)*8 + i]   (RoPE applied)
// V packed frag (transposed): vp[(((b*4+nt)*8+ksg)*64 + L)*8 + i] =
//   V[b][ksg*32 + (L>>4)*8 + i][nt*16 + (L&15)]
__launch_bounds__(512, 6)
__global__ void qkv_kernel(const float* __restrict__ x, const float* __restrict__ cosp,
                           const float* __restrict__ sinp,
                           const unsigned short* __restrict__ wtp,
                           unsigned short* __restrict__ qp,
                           unsigned short* __restrict__ kp,
                           unsigned short* __restrict__ vp) {
  // 48 KB total: x slab; after the K-loop the same region is reused as the
  // Q/K/V staging tiles (one extra barrier).
  __shared__ __align__(16) unsigned short xs[64 * 384];

  unsigned short* Qst = xs;                 // [64][72]
  unsigned short* Kst = xs + 64 * 72;       // [64][72]
  unsigned short* Vst = xs + 2 * 64 * 72;   // [64][72]

  const int tid = threadIdx.x;
  const int w = tid >> 6;        // wave 0..7
  const int lane = tid & 63;
  const int l15 = lane & 15;
  const int lq = lane >> 4;
  const int bk = blockIdx.x;     // 0..4095
  const int b = bk >> 2, g64 = bk & 3;
  const int row0 = g64 * 64;

  const float* xb = x + (size_t)b * T_ * C_ + (size_t)row0 * C_;

  // ---- stage x slab with depth-2 chunk prefetch (chunk = 32 B/thread)
  {
    float4 c0[2], c1[2];
    {
      const float* p = xb + (size_t)tid * 8;
      c0[0] = *(const float4*)p;
      c0[1] = *(const float4*)(p + 4);
    }
    #pragma unroll
    for (int s = 0; s < 6; ++s) {
      if (s + 1 < 6) {
        const float* p = xb + (size_t)((s + 1) * 512 + tid) * 8;
        c1[0] = *(const float4*)p;
        c1[1] = *(const float4*)(p + 4);
      }
      int c = s * 512 + tid;
      int row = c / 48;                 // 48 chunks per row
      int cb = (c - row * 48) * 16;     // byte offset within bf16 row
      bf16x8 v = cvt8(c0[0], c0[1]);
      *(bf16x8*)((char*)xs + row * 768 + (cb ^ ((row & 7) << 4))) = v;
      c0[0] = c1[0]; c0[1] = c1[1];
    }
  }
  __syncthreads();

  // ---- K-loop: wave = (rset = w>>2) x (ng = w&3); 2 row-tiles x 3 n-tiles.
  const int ng = w & 3, rset = w >> 2;

  f32x4 acc[2][3];
  #pragma unroll
  for (int i = 0; i < 2; ++i)
    #pragma unroll
    for (int m = 0; m < 3; ++m) {
      f32x4 z = {0.f, 0.f, 0.f, 0.f};
      acc[i][m] = z;
    }

  const int arow0 = (rset * 2) * 16 + l15;
  const int arow1 = (rset * 2 + 1) * 16 + l15;
  const char* xrow0 = (const char*)xs + arow0 * 768;
  const char* xrow1 = (const char*)xs + arow1 * 768;
  const int asw0 = (arow0 & 7) << 4;
  const int asw1 = (arow1 & 7) << 4;

  #pragma unroll
  for (int ks = 0; ks < 12; ++ks) {
    bf16x8 bv[3];
    #pragma unroll
    for (int m = 0; m < 3; ++m)
      bv[m] = *(const bf16x8*)(wtp + ((size_t)(ks * 12 + ng * 3 + m) * 64 + lane) * 8);
    bf16x8 a0 = *(const bf16x8*)(xrow0 + ((ks * 64 + lq * 16) ^ asw0));
    bf16x8 a1 = *(const bf16x8*)(xrow1 + ((ks * 64 + lq * 16) ^ asw1));
    #pragma unroll
    for (int m = 0; m < 3; ++m) {
      acc[0][m] = __builtin_amdgcn_mfma_f32_16x16x32_bf16(a0, bv[m], acc[0][m], 0, 0, 0);
      acc[1][m] = __builtin_amdgcn_mfma_f32_16x16x32_bf16(a1, bv[m], acc[1][m], 0, 0, 0);
    }
  }
  __syncthreads();   // all waves done reading xs before it is overwritten

  // ---- scatter-stage accumulators (pre-RoPE) into staging tiles (xs region)
  #pragma unroll
  for (int i = 0; i < 2; ++i) {
    #pragma unroll
    for (int m = 0; m < 3; ++m) {
      const int nt = ng * 3 + m;
      #pragma unroll
      for (int j = 0; j < 4; ++j) {
        const int r64 = (rset * 2 + i) * 16 + lq * 4 + j;
        unsigned short v = f2bf(acc[i][m][j]);
        if (nt < 4)      Qst[r64 * 72 + nt * 16 + l15] = v;
        else if (nt < 8) Kst[r64 * 72 + (nt - 4) * 16 + l15] = v;
        else             Vst[((nt - 8) * 16 + l15) * 72 + r64] = v;
      }
    }
  }
  __syncthreads();

  // ---- frag-line writeout: 24 x 1KB lines (Q 8, K 8, V 8); RoPE fused on Q/K
  #pragma unroll
  for (int pass = 0; pass < 3; ++pass) {
    const int id = pass * 8 + w;
    if (id < 16) {
      const unsigned short* S = (id < 8) ? Qst : Kst;
      unsigned short* dst = (id < 8) ? qp : kp;
      const int lid = id & 7;
      const int tl = lid >> 1;          // tile within 64-row slab (0..3)
      const int ks2 = lid & 1;
      const int r64 = tl * 16 + l15;
      const int c0 = ks2 * 32 + lq * 8;
      const unsigned short* rowp = S + r64 * 72;
      bf16x8 mv = *(const bf16x8*)(rowp + c0);
      bf16x8 pv = *(const bf16x8*)(rowp + (c0 ^ 32));
      const int tglob = row0 + r64;
      const float* cp = cosp + tglob * H_ + c0;
      const float* sp = sinp + tglob * H_ + c0;
      float4 ca = *(const float4*)cp, cb = *(const float4*)(cp + 4);
      float4 sa = *(const float4*)sp, sb = *(const float4*)(sp + 4);
      const float sgn = ks2 ? 1.0f : -1.0f;
      bf16x8 ov;
      ov[0] = (short)f2bf(bf2f((unsigned short)mv[0]) * ca.x + sgn * bf2f((unsigned short)pv[0]) * sa.x);
      ov[1] = (short)f2bf(bf2f((unsigned short)mv[1]) * ca.y + sgn * bf2f((unsigned short)pv[1]) * sa.y);
      ov[2] = (short)f2bf(bf2f((unsigned short)mv[2]) * ca.z + sgn * bf2f((unsigned short)pv[2]) * sa.z);
      ov[3] = (short)f2bf(bf2f((unsigned short)mv[3]) * ca.w + sgn * bf2f((unsigned short)pv[3]) * sa.w);
      ov[4] = (short)f2bf(bf2f((unsigned short)mv[4]) * cb.x + sgn * bf2f((unsigned short)pv[4]) * sb.x);
      ov[5] = (short)f2bf(bf2f((unsigned short)mv[5]) * cb.y + sgn * bf2f((unsigned short)pv[5]) * sb.y);
      ov[6] = (short)f2bf(bf2f((unsigned short)mv[6]) * cb.z + sgn * bf2f((unsigned short)pv[6]) * sb.z);
      ov[7] = (short)f2bf(bf2f((unsigned short)mv[7]) * cb.w + sgn * bf2f((unsigned short)pv[7]) * sb.w);
      const int tile_glob = g64 * 4 + tl;
      *(bf16x8*)(dst + ((((size_t)b * 16 + tile_glob) * 2 + ks2) * 64 + lane) * 8) = ov;
    } else if (id < 24) {
      const int lid = id - 16;
      const int ntv = lid >> 1;
      const int kgl = lid & 1;          // which 32-row half of the slab
      const int ksg = g64 * 2 + kgl;
      bf16x8 fr = *(const bf16x8*)(Vst + (ntv * 16 + l15) * 72 + kgl * 32 + lq * 8);
      *(bf16x8*)(vp + ((((size_t)b * 4 + ntv) * 8 + ksg) * 64 + lane) * 8) = fr;
    }
  }
}

__launch_bounds__(256, 4)
__global__ void attn_kernel(const unsigned short* __restrict__ qp,
                            const unsigned short* __restrict__ kp,
                            const unsigned short* __restrict__ vp,
                            float* __restrict__ out) {
  __shared__ unsigned short Plds[4 * 16 * 264];

  const int tid = threadIdx.x;
  const int w = tid >> 6;
  const int lane = tid & 63;
  const int l15 = lane & 15;
  const int lq = lane >> 4;
  // Same-XCD pairing: blocks b and b+1024 (same batch) share an XCD
  // (1024 % 8 == 0 under round-robin) -> overlapping K/V reads hit L2.
  const int bk = blockIdx.x;
  const int b = bk & 1023, half = bk >> 10;
  const int rt2[2] = {half * 8 + w, half * 8 + 7 - w};

  unsigned short* Pw = Plds + w * 16 * 264;
  float* ob = out + (size_t)b * T_ * H_;

  #pragma unroll
  for (int i = 0; i < 2; ++i) {
    const int ti = rt2[i];
    const int t0 = ti * 16;

    bf16x8 aq[2];
    #pragma unroll
    for (int ks2 = 0; ks2 < 2; ++ks2)
      aq[ks2] = *(const bf16x8*)(qp + ((((size_t)b * 16 + ti) * 2 + ks2) * 64 + lane) * 8);

    f32x4 sacc[16];
    #pragma unroll
    for (int si = 0; si < 16; ++si) {
      f32x4 z = {0.f, 0.f, 0.f, 0.f};
      sacc[si] = z;
    }

    #pragma unroll
    for (int si = 0; si < 16; ++si) {
      if (si <= ti) {  // wave-uniform causal tile skip
        #pragma unroll
        for (int ks2 = 0; ks2 < 2; ++ks2) {
          bf16x8 bkf = *(const bf16x8*)(kp + ((((size_t)b * 16 + si) * 2 + ks2) * 64 + lane) * 8);
          sacc[si] = __builtin_amdgcn_mfma_f32_16x16x32_bf16(aq[ks2], bkf, sacc[si], 0, 0, 0);
        }
      }
    }

    int trow = t0 + lq * 4;
    #pragma unroll
    for (int si = 0; si < 16; ++si) {
      #pragma unroll
      for (int j = 0; j < 4; ++j) {
        float s = sacc[si][j] * 0.125f;
        if (si * 16 + l15 > trow + j) s = -1e30f;
        sacc[si][j] = s;
      }
    }

    float rl[4];
    #pragma unroll
    for (int j = 0; j < 4; ++j) {
      float mj = -1e30f;
      #pragma unroll
      for (int si = 0; si < 16; ++si) mj = fmaxf(mj, sacc[si][j]);
      #pragma unroll
      for (int d = 1; d < 16; d <<= 1) mj = fmaxf(mj, __shfl_xor(mj, d));
      float lj = 0.0f;
      #pragma unroll
      for (int si = 0; si < 16; ++si) {
        float p = __expf(sacc[si][j] - mj);
        lj += p;
        Pw[(lq * 4 + j) * 264 + si * 16 + l15] = f2bf(p);
      }
      #pragma unroll
      for (int d = 1; d < 16; d <<= 1) lj += __shfl_xor(lj, d);
      rl[j] = 1.0f / lj;
    }

    f32x4 oacc[4];
    #pragma unroll
    for (int nt = 0; nt < 4; ++nt) {
      f32x4 z = {0.f, 0.f, 0.f, 0.f};
      oacc[nt] = z;
    }
    int nk = (t0 + 16 + 31) >> 5;
    for (int ks = 0; ks < nk; ++ks) {
      bf16x8 ap = *(const bf16x8*)&Pw[l15 * 264 + ks * 32 + lq * 8];
      #pragma unroll
      for (int nt = 0; nt < 4; ++nt) {
        bf16x8 bv = *(const bf16x8*)(vp + ((((size_t)b * 4 + nt) * 8 + ks) * 64 + lane) * 8);
        oacc[nt] = __builtin_amdgcn_mfma_f32_16x16x32_bf16(ap, bv, oacc[nt], 0, 0, 0);
      }
    }

    #pragma unroll
    for (int nt = 0; nt < 4; ++nt)
      #pragma unroll
      for (int j = 0; j < 4; ++j)
        ob[(t0 + lq * 4 + j) * H_ + nt * 16 + l15] = oacc[nt][j] * rl[j];
  }
}

extern "C" void kernel_launch(void* const* d_in, const int* in_sizes, int n_in,
                              void* d_out, int out_size, void* d_ws, size_t ws_size,
                              hipStream_t stream) {
  const float* x    = (const float*)d_in[0];
  const float* cosp = (const float*)d_in[1];
  const float* sinp = (const float*)d_in[2];
  const float* Wq   = (const float*)d_in[3];
  const float* Wk   = (const float*)d_in[4];
  const float* Wv   = (const float*)d_in[5];
  float* out = (float*)d_out;

  const size_t wtp_bytes = 144 * 512 * 2;
  const size_t frag_elems = (size_t)B_ * 16 * 2 * 64 * 8;

  unsigned short* wtp = (unsigned short*)d_ws;
  unsigned short* qp = (unsigned short*)((char*)d_ws + wtp_bytes);
  unsigned short* kp = qp + frag_elems;
  unsigned short* vp = kp + frag_elems;
  (void)ws_size;

  pack_w_frag<<<288, 256, 0, stream>>>(Wq, Wk, Wv, wtp);
  qkv_kernel<<<4096, 512, 0, stream>>>(x, cosp, sinp, wtp, qp, kp, vp);
  attn_kernel<<<B_ * 2, 256, 0, stream>>>(qp, kp, vp, out);
}